// Round 5
// baseline (1218.583 us; speedup 1.0000x reference)
//
#include <hip/hip_runtime.h>
#include <hip/hip_bf16.h>
#include <cstdint>

constexpr int LSEQ  = 384;
constexpr int BATCH = 8;
constexpr int HID   = 512;
constexpr int NHEAD = 8;
constexpr int DKH   = 64;
constexpr int NLAY  = 4;
constexpr int BL    = BATCH * LSEQ;      // 3072 rows
constexpr int LL2   = LSEQ * LSEQ;       // 147456 pairs per batch
constexpr int BH    = BATCH * NHEAD;     // 64

typedef __bf16 bf16x8 __attribute__((ext_vector_type(8)));
typedef float  f32x4  __attribute__((ext_vector_type(4)));

__device__ inline bf16x8 load_frag(const __hip_bfloat16* p) {
    uint4 u = *reinterpret_cast<const uint4*>(p);
    return __builtin_bit_cast(bf16x8, u);
}
__device__ inline f32x4 mfma16(bf16x8 a, bf16x8 b, f32x4 c) {
    return __builtin_amdgcn_mfma_f32_16x16x32_bf16(a, b, c, 0, 0, 0);
}
__device__ inline float b2f(__hip_bfloat16 v) { return __bfloat162float(v); }

// ---------------------------------------------------------------------------
// Normalize mask storage (u8 / i32 / i64 / bf16 / f32 bools) -> uchar[3072].
__global__ __launch_bounds__(1024) void mask_norm_kernel(
    const unsigned char* __restrict__ raw, unsigned char* __restrict__ m)
{
    __shared__ int fl;
    const int tid = threadIdx.x;
    if (tid == 0) fl = 0;
    __syncthreads();
    int f = 0;
    for (int i = tid; i < BL; i += 1024) {
        const unsigned char v = raw[i];
        if (v > 1) f |= 1;                      // float-family encoding
        if (v && (i & 3)) f |= 2;               // nonzero off 4-byte grid -> u8
        if (v && ((i & 7) == 4)) f |= 4;        // byte4 of 8 -> i32
        if (v && ((i & 3) <= 1)) f |= 8;        // float-family: bf16 vs f32
    }
    if (f) atomicOr(&fl, f);
    __syncthreads();
    const int ff = fl;
    int stride, off;
    if (ff & 1) { if (ff & 8) { stride = 2; off = 0; } else { stride = 4; off = 2; } }
    else if (ff & 2) { stride = 1; off = 0; }
    else if (ff & 4) { stride = 4; off = 0; }
    else             { stride = 8; off = 0; }
    for (int i = tid; i < BL; i += 1024)
        m[i] = raw[(size_t)i * stride + off] ? 1 : 0;
}

// ---------------------------------------------------------------------------
// Weight convert+transpose: W[4][512][512] fp32 -> WT[mat][layer][n][k] bf16
__global__ __launch_bounds__(256) void wconv_kernel(
    const float* __restrict__ Wq, const float* __restrict__ Wk,
    const float* __restrict__ Wv, const float* __restrict__ Wo,
    unsigned short* __restrict__ WT)
{
    __shared__ float tile[32][33];
    const int t = blockIdx.x;
    const int ml = t >> 8;            // 0..15: mat*4 + layer
    const int rest = t & 255;
    const int mi = ml >> 2, l = ml & 3;
    const int tk = (rest & 15) * 32;
    const int tn = (rest >> 4) * 32;
    const float* W = (mi == 0) ? Wq : (mi == 1) ? Wk : (mi == 2) ? Wv : Wo;
    const float* src = W + (size_t)l * HID * HID;
    const int c = threadIdx.x & 31, r = threadIdx.x >> 5;
    for (int rr = r; rr < 32; rr += 8)
        tile[rr][c] = src[(size_t)(tk + rr) * HID + tn + c];
    __syncthreads();
    unsigned short* dst = WT + (size_t)ml * HID * HID;
    for (int rr = r; rr < 32; rr += 8) {
        __hip_bfloat16 bv = __float2bfloat16(tile[c][rr]);
        dst[(size_t)(tn + rr) * HID + tk + c] = *(unsigned short*)&bv;
    }
}

// ---------------------------------------------------------------------------
// pack: h = x * mask (fp32 + bf16 copies). grid 6144 x 256
__global__ __launch_bounds__(256) void pack_kernel(
    const float* __restrict__ x, const unsigned char* __restrict__ mask,
    float* __restrict__ h, __hip_bfloat16* __restrict__ hb)
{
    const int idx = blockIdx.x * 256 + threadIdx.x;   // < 1572864
    const int row = idx >> 9;
    const float v = mask[row] ? x[idx] : 0.f;
    h[idx] = v;
    hb[idx] = __float2bfloat16(v);
}

// ---------------------------------------------------------------------------
// refCov MLP for ALL 4 layers: logits[l][b][o][i][j] bf16. grid 4608 x 256
__global__ __launch_bounds__(256) void refmlp_kernel(
    const float* __restrict__ refCov,
    const float* __restrict__ Wr1, const float* __restrict__ br1,
    const float* __restrict__ Wr2, const float* __restrict__ br2,
    __hip_bfloat16* __restrict__ refL)
{
    __shared__ unsigned short ldsb[256 * 53];                 // 27 KB (bf16)
    __shared__ float w1[53 * 32], b1s[32], w2[32 * 8], b2s[8];// ~8 KB
    const int tid = threadIdx.x;
    const size_t p0 = (size_t)blockIdx.x * 256;
    const float* src = refCov + p0 * 53;
    for (int i = tid; i < 256 * 53; i += 256) {
        __hip_bfloat16 bv = __float2bfloat16(src[i]);
        ldsb[i] = *(unsigned short*)&bv;
    }
    const int lbase = tid * 53;
    const int p = (int)p0 + tid;
    const int b = p / LL2;
    const int rem = p % LL2;          // i*LSEQ + j
    for (int l = 0; l < NLAY; ++l) {
        __syncthreads();              // ldsb ready / prev-layer weight reads done
        for (int i = tid; i < 53 * 32; i += 256) w1[i] = Wr1[l * 53 * 32 + i];
        w2[tid & 255] = Wr2[l * 256 + (tid & 255)];   // exactly 256 elements
        if (tid < 32) b1s[tid] = br1[l * 32 + tid];
        if (tid < 8)  b2s[tid] = br2[l * 8 + tid];
        __syncthreads();
        float acc[32];
        #pragma unroll
        for (int hh = 0; hh < 32; ++hh) acc[hh] = b1s[hh];
        for (int k2 = 0; k2 < 53; ++k2) {
            __hip_bfloat16 rb; *(unsigned short*)&rb = ldsb[lbase + k2];
            const float r = b2f(rb);
            const float* w = w1 + k2 * 32;
            #pragma unroll
            for (int hh = 0; hh < 32; ++hh) acc[hh] = fmaf(r, w[hh], acc[hh]);
        }
        #pragma unroll
        for (int hh = 0; hh < 32; ++hh) acc[hh] = fmaxf(acc[hh], 0.f);
        #pragma unroll
        for (int o = 0; o < 8; ++o) {
            float s = b2s[o];
            #pragma unroll
            for (int hh = 0; hh < 32; ++hh) s = fmaf(acc[hh], w2[hh * 8 + o], s);
            refL[(size_t)((l * 8 + b) * 8 + o) * LL2 + rem] = __float2bfloat16(s);
        }
    }
}

// ---------------------------------------------------------------------------
// Projection GEMM: C[3072,512] = A[3072,512] @ BT^T (+bias)
// modes: 0=Q(bf16 [b][h][i][d], *scale) 1=K(same,1.0) 2=V(bf16 [b][h][d][i]) 3=O(fp32 rowmajor)
__global__ __launch_bounds__(256) void gemm_proj_kernel(
    const __hip_bfloat16* __restrict__ A,
    const __hip_bfloat16* __restrict__ BT,
    const float* __restrict__ bias,
    __hip_bfloat16* __restrict__ outb,
    float* __restrict__ outf,
    int mode, float scale)
{
    const int bm = blockIdx.x % (BL / 64);
    const int bn = blockIdx.x / (BL / 64);
    const int wv = threadIdx.x >> 6;
    const int lane = threadIdx.x & 63;
    const int lr = lane & 15, quad = lane >> 4;
    const int m0 = bm * 64 + (wv & 1) * 32;
    const int n0 = bn * 64 + (wv >> 1) * 32;
    f32x4 acc[2][2];
    #pragma unroll
    for (int i = 0; i < 2; ++i)
        #pragma unroll
        for (int j = 0; j < 2; ++j) acc[i][j] = (f32x4){0.f, 0.f, 0.f, 0.f};
    const __hip_bfloat16* a0p = A + (size_t)(m0 + lr) * HID;
    const __hip_bfloat16* a1p = A + (size_t)(m0 + 16 + lr) * HID;
    const __hip_bfloat16* b0p = BT + (size_t)(n0 + lr) * HID;
    const __hip_bfloat16* b1p = BT + (size_t)(n0 + 16 + lr) * HID;
    #pragma unroll 4
    for (int k0 = 0; k0 < HID; k0 += 32) {
        const int ka = k0 + quad * 8;
        bf16x8 a0 = load_frag(a0p + ka);
        bf16x8 a1 = load_frag(a1p + ka);
        bf16x8 b0 = load_frag(b0p + ka);
        bf16x8 b1 = load_frag(b1p + ka);
        acc[0][0] = mfma16(a0, b0, acc[0][0]);
        acc[0][1] = mfma16(a0, b1, acc[0][1]);
        acc[1][0] = mfma16(a1, b0, acc[1][0]);
        acc[1][1] = mfma16(a1, b1, acc[1][1]);
    }
    #pragma unroll
    for (int mi = 0; mi < 2; ++mi)
        #pragma unroll
        for (int ni = 0; ni < 2; ++ni)
            #pragma unroll
            for (int r = 0; r < 4; ++r) {
                const int m = m0 + mi * 16 + quad * 4 + r;
                const int n = n0 + ni * 16 + lr;
                float v = acc[mi][ni][r];
                if (mode == 3) {
                    outf[(size_t)m * HID + n] = v + bias[n];
                } else {
                    v = (v + bias[n]) * scale;
                    const int bb = m / LSEQ, ii = m % LSEQ;
                    const int hh = n >> 6, d = n & 63;
                    if (mode == 2)
                        outb[((size_t)(bb * NHEAD + hh) * DKH + d) * LSEQ + ii] = __float2bfloat16(v);
                    else
                        outb[((size_t)(bb * NHEAD + hh) * LSEQ + ii) * DKH + d] = __float2bfloat16(v);
                }
            }
}

// ---------------------------------------------------------------------------
// scores: S[bh][i][j] = sum_d q[bh][i][d]*k[bh][j][d]  (q pre-scaled)
__global__ __launch_bounds__(256) void gemm_scores_kernel(
    const __hip_bfloat16* __restrict__ Q,
    const __hip_bfloat16* __restrict__ Km,
    float* __restrict__ S)
{
    const int bh = blockIdx.x / 36;
    const int t = blockIdx.x % 36;
    const int bm = t % 6, bn = t / 6;
    const int wv = threadIdx.x >> 6;
    const int lane = threadIdx.x & 63;
    const int lr = lane & 15, quad = lane >> 4;
    const int m0 = bm * 64 + (wv & 1) * 32;
    const int n0 = bn * 64 + (wv >> 1) * 32;
    const __hip_bfloat16* qb = Q + (size_t)bh * LSEQ * DKH;
    const __hip_bfloat16* kb = Km + (size_t)bh * LSEQ * DKH;
    f32x4 acc[2][2];
    #pragma unroll
    for (int i = 0; i < 2; ++i)
        #pragma unroll
        for (int j = 0; j < 2; ++j) acc[i][j] = (f32x4){0.f, 0.f, 0.f, 0.f};
    #pragma unroll
    for (int k0 = 0; k0 < DKH; k0 += 32) {
        const int ka = k0 + quad * 8;
        bf16x8 a0 = load_frag(qb + (size_t)(m0 + lr) * DKH + ka);
        bf16x8 a1 = load_frag(qb + (size_t)(m0 + 16 + lr) * DKH + ka);
        bf16x8 b0 = load_frag(kb + (size_t)(n0 + lr) * DKH + ka);
        bf16x8 b1 = load_frag(kb + (size_t)(n0 + 16 + lr) * DKH + ka);
        acc[0][0] = mfma16(a0, b0, acc[0][0]);
        acc[0][1] = mfma16(a0, b1, acc[0][1]);
        acc[1][0] = mfma16(a1, b0, acc[1][0]);
        acc[1][1] = mfma16(a1, b1, acc[1][1]);
    }
    float* srow = S + (size_t)bh * LL2;
    #pragma unroll
    for (int mi = 0; mi < 2; ++mi)
        #pragma unroll
        for (int ni = 0; ni < 2; ++ni)
            #pragma unroll
            for (int r = 0; r < 4; ++r) {
                const int m = m0 + mi * 16 + quad * 4 + r;
                const int n = n0 + ni * 16 + lr;
                srow[(size_t)m * LSEQ + n] = acc[mi][ni][r];
            }
}

// ---------------------------------------------------------------------------
// softmax+combine: comb = 0.5*(softmax(S_masked) + softmax(ref_masked)), bf16
__global__ __launch_bounds__(256) void softmax_comb_kernel(
    const float* __restrict__ S, const __hip_bfloat16* __restrict__ refl,
    const unsigned char* __restrict__ mask, __hip_bfloat16* __restrict__ comb)
{
    const int wv = threadIdx.x >> 6, lane = threadIdx.x & 63;
    const int row = blockIdx.x * 4 + wv;      // bh*LSEQ + i
    const int bh = row / LSEQ, i = row % LSEQ;
    const int b = bh >> 3;
    const size_t roff = (size_t)row * LSEQ;
    __hip_bfloat16* crow = comb + roff;
    if (!mask[b * LSEQ + i]) {
        const __hip_bfloat16 z = __float2bfloat16(0.f);
        #pragma unroll
        for (int t = 0; t < 6; ++t) crow[lane + 64 * t] = z;
        return;
    }
    const float* srow = S + roff;
    const __hip_bfloat16* rrow = refl + roff;
    float sv[6], rv[6];
    #pragma unroll
    for (int t = 0; t < 6; ++t) {
        const int j = lane + 64 * t;
        const bool vm = mask[b * LSEQ + j] != 0;
        sv[t] = vm ? srow[j] : -1e30f;
        rv[t] = vm ? b2f(rrow[j]) : -1e30f;
    }
    float ms = -1e30f, mr = -1e30f;
    #pragma unroll
    for (int t = 0; t < 6; ++t) { ms = fmaxf(ms, sv[t]); mr = fmaxf(mr, rv[t]); }
    #pragma unroll
    for (int off = 32; off > 0; off >>= 1) {
        ms = fmaxf(ms, __shfl_xor(ms, off));
        mr = fmaxf(mr, __shfl_xor(mr, off));
    }
    float es[6], er[6], Ss = 0.f, Sr = 0.f;
    #pragma unroll
    for (int t = 0; t < 6; ++t) {
        es[t] = __expf(sv[t] - ms); Ss += es[t];
        er[t] = __expf(rv[t] - mr); Sr += er[t];
    }
    #pragma unroll
    for (int off = 32; off > 0; off >>= 1) {
        Ss += __shfl_xor(Ss, off);
        Sr += __shfl_xor(Sr, off);
    }
    const float cs = 0.5f / Ss, cr = 0.5f / Sr;
    #pragma unroll
    for (int t = 0; t < 6; ++t)
        crow[lane + 64 * t] = __float2bfloat16(es[t] * cs + er[t] * cr);
}

// ---------------------------------------------------------------------------
// out = comb @ v : AO[b*LSEQ+i][h*64+d] bf16.  grid 384 x 256 (64 bh x 6 m)
__global__ __launch_bounds__(256) void gemm_out_kernel(
    const __hip_bfloat16* __restrict__ C,   // comb [64][384][384]
    const __hip_bfloat16* __restrict__ VT,  // [64][64][384]
    __hip_bfloat16* __restrict__ AO)
{
    const int bh = blockIdx.x / 6;
    const int bm = blockIdx.x % 6;
    const int wv = threadIdx.x >> 6;
    const int lane = threadIdx.x & 63;
    const int lr = lane & 15, quad = lane >> 4;
    const int m0 = bm * 64 + (wv & 1) * 32;
    const int n0 = (wv >> 1) * 32;
    const __hip_bfloat16* cb = C + (size_t)bh * LL2;
    const __hip_bfloat16* vb = VT + (size_t)bh * DKH * LSEQ;
    f32x4 acc[2][2];
    #pragma unroll
    for (int i = 0; i < 2; ++i)
        #pragma unroll
        for (int j = 0; j < 2; ++j) acc[i][j] = (f32x4){0.f, 0.f, 0.f, 0.f};
    #pragma unroll 4
    for (int k0 = 0; k0 < LSEQ; k0 += 32) {
        const int ka = k0 + quad * 8;
        bf16x8 a0 = load_frag(cb + (size_t)(m0 + lr) * LSEQ + ka);
        bf16x8 a1 = load_frag(cb + (size_t)(m0 + 16 + lr) * LSEQ + ka);
        bf16x8 b0 = load_frag(vb + (size_t)(n0 + lr) * LSEQ + ka);
        bf16x8 b1 = load_frag(vb + (size_t)(n0 + 16 + lr) * LSEQ + ka);
        acc[0][0] = mfma16(a0, b0, acc[0][0]);
        acc[0][1] = mfma16(a0, b1, acc[0][1]);
        acc[1][0] = mfma16(a1, b0, acc[1][0]);
        acc[1][1] = mfma16(a1, b1, acc[1][1]);
    }
    const int bb = bh >> 3, hh = bh & 7;
    #pragma unroll
    for (int mi = 0; mi < 2; ++mi)
        #pragma unroll
        for (int ni = 0; ni < 2; ++ni)
            #pragma unroll
            for (int r = 0; r < 4; ++r) {
                const int m = m0 + mi * 16 + quad * 4 + r;
                const int n = n0 + ni * 16 + lr;
                AO[(size_t)(bb * LSEQ + m) * HID + hh * DKH + n] =
                    __float2bfloat16(acc[mi][ni][r]);
            }
}

// ---------------------------------------------------------------------------
// LayerNorm. flags: 1=add proj, 2=zero masked rows, 4=write bf16. grid 3072 x 256
__global__ __launch_bounds__(256) void ln_kernel(
    const float* __restrict__ resid, const float* __restrict__ proj,
    const float* __restrict__ g, const float* __restrict__ beta,
    float* __restrict__ outf, __hip_bfloat16* __restrict__ outb,
    const unsigned char* __restrict__ mask, int flags)
{
    const int row = blockIdx.x, tid = threadIdx.x;
    const size_t base = (size_t)row * HID;
    float x0 = resid[base + tid], x1 = resid[base + tid + 256];
    if (flags & 1) { x0 += proj[base + tid]; x1 += proj[base + tid + 256]; }
    float s = x0 + x1, s2 = x0 * x0 + x1 * x1;
    #pragma unroll
    for (int off = 32; off > 0; off >>= 1) {
        s += __shfl_xor(s, off);
        s2 += __shfl_xor(s2, off);
    }
    __shared__ float rs[4], rs2[4];
    if ((tid & 63) == 0) { rs[tid >> 6] = s; rs2[tid >> 6] = s2; }
    __syncthreads();
    s = rs[0] + rs[1] + rs[2] + rs[3];
    s2 = rs2[0] + rs2[1] + rs2[2] + rs2[3];
    const float mu = s * (1.f / HID);
    const float var = s2 * (1.f / HID) - mu * mu;
    const float rstd = rsqrtf(var + 1e-5f);
    float y0 = (x0 - mu) * rstd * g[tid] + beta[tid];
    float y1 = (x1 - mu) * rstd * g[tid + 256] + beta[tid + 256];
    if ((flags & 2) && !mask[row]) { y0 = 0.f; y1 = 0.f; }
    outf[base + tid] = y0;
    outf[base + tid + 256] = y1;
    if (flags & 4) {
        outb[base + tid] = __float2bfloat16(y0);
        outb[base + tid + 256] = __float2bfloat16(y1);
    }
}

// ---------------------------------------------------------------------------
// final reduce over sequence: out[b][c] = sum_l hfin[b][l][c] (fp32 out). grid 8 x 512
__global__ __launch_bounds__(512) void reduce_kernel(
    const float* __restrict__ hf, float* __restrict__ out)
{
    const int b = blockIdx.x, c = threadIdx.x;
    float s = 0.f;
    for (int i = 0; i < LSEQ; ++i)
        s += hf[((size_t)(b * LSEQ + i)) * HID + c];
    out[b * HID + c] = s;
}

// ---------------------------------------------------------------------------
extern "C" void kernel_launch(void* const* d_in, const int* in_sizes, int n_in,
                              void* d_out, int out_size, void* d_ws, size_t ws_size,
                              hipStream_t stream)
{
    const float* x   = (const float*)d_in[0];
    const unsigned char* mraw = (const unsigned char*)d_in[1];
    const float* refCov = (const float*)d_in[2];
    const float* Wq = (const float*)d_in[3];
    const float* bq = (const float*)d_in[4];
    const float* Wk = (const float*)d_in[5];
    const float* bk = (const float*)d_in[6];
    const float* Wv = (const float*)d_in[7];
    const float* bv = (const float*)d_in[8];
    const float* Wo = (const float*)d_in[9];
    const float* bo = (const float*)d_in[10];
    const float* Wr1 = (const float*)d_in[11];
    const float* br1 = (const float*)d_in[12];
    const float* Wr2 = (const float*)d_in[13];
    const float* br2 = (const float*)d_in[14];
    const float* ln_g = (const float*)d_in[15];
    const float* ln_b = (const float*)d_in[16];
    const float* fn_g = (const float*)d_in[17];
    const float* fn_b = (const float*)d_in[18];
    float* outp = (float*)d_out;

    char* ws = (char*)d_ws;
    size_t off = 0;
    auto alloc = [&](size_t bytes) -> char* {
        char* p = ws + off;
        off += (bytes + 255) & ~(size_t)255;
        return p;
    };
    __hip_bfloat16* refL = (__hip_bfloat16*)alloc((size_t)NLAY * BH * LL2 * 2);
    float*          h    = (float*)alloc((size_t)BL * HID * 4);
    __hip_bfloat16* hb   = (__hip_bfloat16*)alloc((size_t)BL * HID * 2);
    __hip_bfloat16* q    = (__hip_bfloat16*)alloc((size_t)BH * LSEQ * DKH * 2);
    __hip_bfloat16* kk   = (__hip_bfloat16*)alloc((size_t)BH * LSEQ * DKH * 2);
    __hip_bfloat16* vT   = (__hip_bfloat16*)alloc((size_t)BH * DKH * LSEQ * 2);
    float*          S    = (float*)alloc((size_t)BH * LL2 * 4);
    __hip_bfloat16* comb = (__hip_bfloat16*)alloc((size_t)BH * LL2 * 2);
    __hip_bfloat16* AO   = (__hip_bfloat16*)alloc((size_t)BL * HID * 2);
    float*          proj = (float*)alloc((size_t)BL * HID * 4);
    unsigned short* WT   = (unsigned short*)alloc((size_t)16 * HID * HID * 2);
    unsigned char*  msk  = (unsigned char*)alloc(BL);
    float*          hfin = S;   // S is dead by the final LN; alias it

    mask_norm_kernel<<<1, 1024, 0, stream>>>(mraw, msk);
    wconv_kernel<<<4096, 256, 0, stream>>>(Wq, Wk, Wv, Wo, WT);
    pack_kernel<<<6144, 256, 0, stream>>>(x, msk, h, hb);
    refmlp_kernel<<<4608, 256, 0, stream>>>(refCov, Wr1, br1, Wr2, br2, refL);

    for (int l = 0; l < NLAY; ++l) {
        const __hip_bfloat16* WTq = (const __hip_bfloat16*)(WT + (size_t)(0 * 4 + l) * HID * HID);
        const __hip_bfloat16* WTk = (const __hip_bfloat16*)(WT + (size_t)(1 * 4 + l) * HID * HID);
        const __hip_bfloat16* WTv = (const __hip_bfloat16*)(WT + (size_t)(2 * 4 + l) * HID * HID);
        const __hip_bfloat16* WTo = (const __hip_bfloat16*)(WT + (size_t)(3 * 4 + l) * HID * HID);
        gemm_proj_kernel<<<384, 256, 0, stream>>>(hb, WTq, bq + l * HID, q,  nullptr, 0, 0.125f);
        gemm_proj_kernel<<<384, 256, 0, stream>>>(hb, WTk, bk + l * HID, kk, nullptr, 1, 1.0f);
        gemm_proj_kernel<<<384, 256, 0, stream>>>(hb, WTv, bv + l * HID, vT, nullptr, 2, 1.0f);
        gemm_scores_kernel<<<2304, 256, 0, stream>>>(q, kk, S);
        softmax_comb_kernel<<<6144, 256, 0, stream>>>(S, refL + (size_t)l * BH * LL2, msk, comb);
        gemm_out_kernel<<<384, 256, 0, stream>>>(comb, vT, AO);
        gemm_proj_kernel<<<384, 256, 0, stream>>>(AO, WTo, bo + l * HID, nullptr, proj, 3, 1.0f);
        ln_kernel<<<3072, 256, 0, stream>>>(h, proj, ln_g + l * HID, ln_b + l * HID,
                                            h, hb, nullptr, 1 | 4);
    }
    ln_kernel<<<3072, 256, 0, stream>>>(h, nullptr, fn_g, fn_b, hfin, nullptr, msk, 2);
    reduce_kernel<<<8, 512, 0, stream>>>(hfin, outp);
}

// Round 6
// 1050.870 us; speedup vs baseline: 1.1596x; 1.1596x over previous
//
#include <hip/hip_runtime.h>
#include <hip/hip_bf16.h>
#include <cstdint>

constexpr int LSEQ  = 384;
constexpr int BATCH = 8;
constexpr int HID   = 512;
constexpr int NHEAD = 8;
constexpr int DKH   = 64;
constexpr int NLAY  = 4;
constexpr int BL    = BATCH * LSEQ;      // 3072 rows
constexpr int LL2   = LSEQ * LSEQ;       // 147456 pairs per batch
constexpr int BH    = BATCH * NHEAD;     // 64

typedef __bf16 bf16x8 __attribute__((ext_vector_type(8)));
typedef float  f32x4  __attribute__((ext_vector_type(4)));

__device__ inline bf16x8 load_frag(const void* p) {
    uint4 u = *reinterpret_cast<const uint4*>(p);
    return __builtin_bit_cast(bf16x8, u);
}
__device__ inline f32x4 mfma16(bf16x8 a, bf16x8 b, f32x4 c) {
    return __builtin_amdgcn_mfma_f32_16x16x32_bf16(a, b, c, 0, 0, 0);
}
__device__ inline float b2f(__hip_bfloat16 v) { return __bfloat162float(v); }
__device__ inline unsigned short bfbits(float f) {
    __hip_bfloat16 b = __float2bfloat16(f);
    return *(unsigned short*)&b;
}

// ---------------------------------------------------------------------------
// Normalize mask storage (u8 / i32 / i64 / bf16 / f32 bools) -> uchar[3072].
__global__ __launch_bounds__(1024) void mask_norm_kernel(
    const unsigned char* __restrict__ raw, unsigned char* __restrict__ m)
{
    __shared__ int fl;
    const int tid = threadIdx.x;
    if (tid == 0) fl = 0;
    __syncthreads();
    int f = 0;
    for (int i = tid; i < BL; i += 1024) {
        const unsigned char v = raw[i];
        if (v > 1) f |= 1;
        if (v && (i & 3)) f |= 2;
        if (v && ((i & 7) == 4)) f |= 4;
        if (v && ((i & 3) <= 1)) f |= 8;
    }
    if (f) atomicOr(&fl, f);
    __syncthreads();
    const int ff = fl;
    int stride, off;
    if (ff & 1) { if (ff & 8) { stride = 2; off = 0; } else { stride = 4; off = 2; } }
    else if (ff & 2) { stride = 1; off = 0; }
    else if (ff & 4) { stride = 4; off = 0; }
    else             { stride = 8; off = 0; }
    for (int i = tid; i < BL; i += 1024)
        m[i] = raw[(size_t)i * stride + off] ? 1 : 0;
}

// ---------------------------------------------------------------------------
// Weight convert+transpose: W[4][512][512] fp32 -> WT[mat][layer][n][k] bf16
__global__ __launch_bounds__(256) void wconv_kernel(
    const float* __restrict__ Wq, const float* __restrict__ Wk,
    const float* __restrict__ Wv, const float* __restrict__ Wo,
    unsigned short* __restrict__ WT)
{
    __shared__ float tile[32][33];
    const int t = blockIdx.x;
    const int ml = t >> 8;
    const int rest = t & 255;
    const int mi = ml >> 2, l = ml & 3;
    const int tk = (rest & 15) * 32;
    const int tn = (rest >> 4) * 32;
    const float* W = (mi == 0) ? Wq : (mi == 1) ? Wk : (mi == 2) ? Wv : Wo;
    const float* src = W + (size_t)l * HID * HID;
    const int c = threadIdx.x & 31, r = threadIdx.x >> 5;
    for (int rr = r; rr < 32; rr += 8)
        tile[rr][c] = src[(size_t)(tk + rr) * HID + tn + c];
    __syncthreads();
    unsigned short* dst = WT + (size_t)ml * HID * HID;
    for (int rr = r; rr < 32; rr += 8)
        dst[(size_t)(tn + rr) * HID + tk + c] = bfbits(tile[c][rr]);
}

// ---------------------------------------------------------------------------
// pack: h = x * mask (fp32 + bf16 copies). grid 6144 x 256
__global__ __launch_bounds__(256) void pack_kernel(
    const float* __restrict__ x, const unsigned char* __restrict__ mask,
    float* __restrict__ h, __hip_bfloat16* __restrict__ hb)
{
    const int idx = blockIdx.x * 256 + threadIdx.x;
    const int row = idx >> 9;
    const float v = mask[row] ? x[idx] : 0.f;
    h[idx] = v;
    hb[idx] = __float2bfloat16(v);
}

// ---------------------------------------------------------------------------
// refCov MLP, MFMA version. 256 pairs/block, all 4 layers per block.
// refL[l][b][o][i][j] bf16. grid 4608 x 256.
__global__ __launch_bounds__(256) void refmlp_kernel(
    const float* __restrict__ refCov,
    const float* __restrict__ Wr1, const float* __restrict__ br1,
    const float* __restrict__ Wr2, const float* __restrict__ br2,
    __hip_bfloat16* __restrict__ refL)
{
    __shared__ unsigned short Atile[256 * 72];   // 36864 B, pairs x feat(53->72)
    __shared__ unsigned short W1Ts[32 * 72];     //  4608 B, W1^T[n][k]
    __shared__ unsigned short W2Ts[16 * 40];     //  1280 B, W2^T[n][k] rows 8..15 zero
    __shared__ unsigned short C1s[4 * 64 * 40];  // 20480 B, per-wave relu(h1)
    __shared__ unsigned short Pout[256 * 8];     //  4096 B, final logits
    __shared__ float br1s[32], br2s[8];

    const int tid = threadIdx.x;
    const int w = tid >> 6, lane = tid & 63;
    const int lr = lane & 15, quad = lane >> 4;
    const size_t p0 = (size_t)blockIdx.x * 256;

    // stage 256 pairs x 53 feats -> bf16 LDS (coalesced global reads)
    const float* src = refCov + p0 * 53;
    for (int i = tid; i < 256 * 53; i += 256) {
        const int row = i / 53, col = i - row * 53;
        Atile[row * 72 + col] = bfbits(src[i]);
    }
    for (int c = 53; c < 72; ++c) Atile[tid * 72 + c] = 0;  // pad

    const int b = (int)(p0 / LL2);
    const int rem0 = (int)(p0 - (size_t)b * LL2);
    unsigned short* C1w = C1s + w * (64 * 40);

    for (int l = 0; l < NLAY; ++l) {
        __syncthreads();   // Atile ready / prev-layer LDS reads done
        // stage W1^T (Wr1 is [53][32] row-major -> transpose into [n][k])
        for (int i = tid; i < 53 * 32; i += 256) {
            const int k = i >> 5, n = i & 31;
            W1Ts[n * 72 + k] = bfbits(Wr1[l * 53 * 32 + i]);
        }
        for (int i = tid; i < 32 * 19; i += 256) {   // pad k=53..71
            const int n = i / 19, k = 53 + (i - n * 19);
            W1Ts[n * 72 + k] = 0;
        }
        {   // W2^T: Wr2 [32][8] -> [n][k], rows 8..15 zero
            const int k = tid >> 3, n = tid & 7;
            W2Ts[n * 40 + k] = bfbits(Wr2[l * 256 + tid]);
            W2Ts[(8 + (tid >> 5)) * 40 + (tid & 31)] = 0;
        }
        if (tid < 32) br1s[tid] = br1[l * 32 + tid];
        if (tid < 8)  br2s[tid] = br2[l * 8 + tid];
        __syncthreads();

        // ---- layer 1: [64x64(K)] @ W1 -> [64x32], per wave ----
        f32x4 acc[4][2];
        #pragma unroll
        for (int ni = 0; ni < 2; ++ni) {
            const float bias = br1s[ni * 16 + lr];
            #pragma unroll
            for (int mi = 0; mi < 4; ++mi)
                acc[mi][ni] = (f32x4){bias, bias, bias, bias};
        }
        #pragma unroll
        for (int ks = 0; ks < 64; ks += 32) {
            const int ka = ks + quad * 8;
            bf16x8 bf0 = load_frag(&W1Ts[(0 * 16 + lr) * 72 + ka]);
            bf16x8 bf1 = load_frag(&W1Ts[(1 * 16 + lr) * 72 + ka]);
            #pragma unroll
            for (int mi = 0; mi < 4; ++mi) {
                bf16x8 a = load_frag(&Atile[(w * 64 + mi * 16 + lr) * 72 + ka]);
                acc[mi][0] = mfma16(a, bf0, acc[mi][0]);
                acc[mi][1] = mfma16(a, bf1, acc[mi][1]);
            }
        }
        // relu -> C1 (per-wave region; same-wave LDS ordering suffices)
        #pragma unroll
        for (int mi = 0; mi < 4; ++mi)
            #pragma unroll
            for (int ni = 0; ni < 2; ++ni)
                #pragma unroll
                for (int r = 0; r < 4; ++r)
                    C1w[(mi * 16 + quad * 4 + r) * 40 + ni * 16 + lr] =
                        bfbits(fmaxf(acc[mi][ni][r], 0.f));

        // ---- layer 2: [64x32] @ W2 -> [64x8(padded 16)] ----
        const float bias2 = (lr < 8) ? br2s[lr] : 0.f;
        bf16x8 b2 = load_frag(&W2Ts[lr * 40 + quad * 8]);
        #pragma unroll
        for (int mi = 0; mi < 4; ++mi) {
            f32x4 acc2 = (f32x4){bias2, bias2, bias2, bias2};
            bf16x8 a2 = load_frag(&C1w[(mi * 16 + lr) * 40 + quad * 8]);
            acc2 = mfma16(a2, b2, acc2);
            if (lr < 8)
                #pragma unroll
                for (int r = 0; r < 4; ++r)
                    Pout[(w * 64 + mi * 16 + quad * 4 + r) * 8 + lr] = bfbits(acc2[r]);
        }
        // coalesced global write: one o-plane at a time (same-wave rows)
        const size_t planeBase = ((size_t)(l * 8 + b) * 8) * LL2 + rem0;
        #pragma unroll
        for (int o = 0; o < 8; ++o) {
            unsigned short pv = Pout[tid * 8 + o];
            *((unsigned short*)refL + planeBase + (size_t)o * LL2 + tid) = pv;
        }
    }
}

// ---------------------------------------------------------------------------
// Projection GEMM: C[3072,512] = A[3072,512] @ BT^T (+bias)
// modes: 0=Q(bf16 [b][h][i][d], *scale) 1=K(same,1.0) 2=V(bf16 [b][h][d][i]) 3=O(fp32 rowmajor)
__global__ __launch_bounds__(256) void gemm_proj_kernel(
    const __hip_bfloat16* __restrict__ A,
    const __hip_bfloat16* __restrict__ BT,
    const float* __restrict__ bias,
    __hip_bfloat16* __restrict__ outb,
    float* __restrict__ outf,
    int mode, float scale)
{
    const int bm = blockIdx.x % (BL / 64);
    const int bn = blockIdx.x / (BL / 64);
    const int wv = threadIdx.x >> 6;
    const int lane = threadIdx.x & 63;
    const int lr = lane & 15, quad = lane >> 4;
    const int m0 = bm * 64 + (wv & 1) * 32;
    const int n0 = bn * 64 + (wv >> 1) * 32;
    f32x4 acc[2][2];
    #pragma unroll
    for (int i = 0; i < 2; ++i)
        #pragma unroll
        for (int j = 0; j < 2; ++j) acc[i][j] = (f32x4){0.f, 0.f, 0.f, 0.f};
    const __hip_bfloat16* a0p = A + (size_t)(m0 + lr) * HID;
    const __hip_bfloat16* a1p = A + (size_t)(m0 + 16 + lr) * HID;
    const __hip_bfloat16* b0p = BT + (size_t)(n0 + lr) * HID;
    const __hip_bfloat16* b1p = BT + (size_t)(n0 + 16 + lr) * HID;
    #pragma unroll 4
    for (int k0 = 0; k0 < HID; k0 += 32) {
        const int ka = k0 + quad * 8;
        bf16x8 a0 = load_frag(a0p + ka);
        bf16x8 a1 = load_frag(a1p + ka);
        bf16x8 b0 = load_frag(b0p + ka);
        bf16x8 b1 = load_frag(b1p + ka);
        acc[0][0] = mfma16(a0, b0, acc[0][0]);
        acc[0][1] = mfma16(a0, b1, acc[0][1]);
        acc[1][0] = mfma16(a1, b0, acc[1][0]);
        acc[1][1] = mfma16(a1, b1, acc[1][1]);
    }
    #pragma unroll
    for (int mi = 0; mi < 2; ++mi)
        #pragma unroll
        for (int ni = 0; ni < 2; ++ni)
            #pragma unroll
            for (int r = 0; r < 4; ++r) {
                const int m = m0 + mi * 16 + quad * 4 + r;
                const int n = n0 + ni * 16 + lr;
                float v = acc[mi][ni][r];
                if (mode == 3) {
                    outf[(size_t)m * HID + n] = v + bias[n];
                } else {
                    v = (v + bias[n]) * scale;
                    const int bb = m / LSEQ, ii = m % LSEQ;
                    const int hh = n >> 6, d = n & 63;
                    if (mode == 2)
                        outb[((size_t)(bb * NHEAD + hh) * DKH + d) * LSEQ + ii] = __float2bfloat16(v);
                    else
                        outb[((size_t)(bb * NHEAD + hh) * LSEQ + ii) * DKH + d] = __float2bfloat16(v);
                }
            }
}

// ---------------------------------------------------------------------------
// scores: S[bh][i][j] = sum_d q[bh][i][d]*k[bh][j][d]  (q pre-scaled)
__global__ __launch_bounds__(256) void gemm_scores_kernel(
    const __hip_bfloat16* __restrict__ Q,
    const __hip_bfloat16* __restrict__ Km,
    float* __restrict__ S)
{
    const int bh = blockIdx.x / 36;
    const int t = blockIdx.x % 36;
    const int bm = t % 6, bn = t / 6;
    const int wv = threadIdx.x >> 6;
    const int lane = threadIdx.x & 63;
    const int lr = lane & 15, quad = lane >> 4;
    const int m0 = bm * 64 + (wv & 1) * 32;
    const int n0 = bn * 64 + (wv >> 1) * 32;
    const __hip_bfloat16* qb = Q + (size_t)bh * LSEQ * DKH;
    const __hip_bfloat16* kb = Km + (size_t)bh * LSEQ * DKH;
    f32x4 acc[2][2];
    #pragma unroll
    for (int i = 0; i < 2; ++i)
        #pragma unroll
        for (int j = 0; j < 2; ++j) acc[i][j] = (f32x4){0.f, 0.f, 0.f, 0.f};
    #pragma unroll
    for (int k0 = 0; k0 < DKH; k0 += 32) {
        const int ka = k0 + quad * 8;
        bf16x8 a0 = load_frag(qb + (size_t)(m0 + lr) * DKH + ka);
        bf16x8 a1 = load_frag(qb + (size_t)(m0 + 16 + lr) * DKH + ka);
        bf16x8 b0 = load_frag(kb + (size_t)(n0 + lr) * DKH + ka);
        bf16x8 b1 = load_frag(kb + (size_t)(n0 + 16 + lr) * DKH + ka);
        acc[0][0] = mfma16(a0, b0, acc[0][0]);
        acc[0][1] = mfma16(a0, b1, acc[0][1]);
        acc[1][0] = mfma16(a1, b0, acc[1][0]);
        acc[1][1] = mfma16(a1, b1, acc[1][1]);
    }
    float* srow = S + (size_t)bh * LL2;
    #pragma unroll
    for (int mi = 0; mi < 2; ++mi)
        #pragma unroll
        for (int ni = 0; ni < 2; ++ni)
            #pragma unroll
            for (int r = 0; r < 4; ++r) {
                const int m = m0 + mi * 16 + quad * 4 + r;
                const int n = n0 + ni * 16 + lr;
                srow[(size_t)m * LSEQ + n] = acc[mi][ni][r];
            }
}

// ---------------------------------------------------------------------------
// softmax+combine: comb = 0.5*(softmax(S_masked) + softmax(ref_masked)), bf16
__global__ __launch_bounds__(256) void softmax_comb_kernel(
    const float* __restrict__ S, const __hip_bfloat16* __restrict__ refl,
    const unsigned char* __restrict__ mask, __hip_bfloat16* __restrict__ comb)
{
    const int wv = threadIdx.x >> 6, lane = threadIdx.x & 63;
    const int row = blockIdx.x * 4 + wv;      // bh*LSEQ + i
    const int bh = row / LSEQ, i = row % LSEQ;
    const int b = bh >> 3;
    const size_t roff = (size_t)row * LSEQ;
    __hip_bfloat16* crow = comb + roff;
    if (!mask[b * LSEQ + i]) {
        const __hip_bfloat16 z = __float2bfloat16(0.f);
        #pragma unroll
        for (int t = 0; t < 6; ++t) crow[lane + 64 * t] = z;
        return;
    }
    const float* srow = S + roff;
    const __hip_bfloat16* rrow = refl + roff;
    float sv[6], rv[6];
    #pragma unroll
    for (int t = 0; t < 6; ++t) {
        const int j = lane + 64 * t;
        const bool vm = mask[b * LSEQ + j] != 0;
        sv[t] = vm ? srow[j] : -1e30f;
        rv[t] = vm ? b2f(rrow[j]) : -1e30f;
    }
    float ms = -1e30f, mr = -1e30f;
    #pragma unroll
    for (int t = 0; t < 6; ++t) { ms = fmaxf(ms, sv[t]); mr = fmaxf(mr, rv[t]); }
    #pragma unroll
    for (int off = 32; off > 0; off >>= 1) {
        ms = fmaxf(ms, __shfl_xor(ms, off));
        mr = fmaxf(mr, __shfl_xor(mr, off));
    }
    float es[6], er[6], Ss = 0.f, Sr = 0.f;
    #pragma unroll
    for (int t = 0; t < 6; ++t) {
        es[t] = __expf(sv[t] - ms); Ss += es[t];
        er[t] = __expf(rv[t] - mr); Sr += er[t];
    }
    #pragma unroll
    for (int off = 32; off > 0; off >>= 1) {
        Ss += __shfl_xor(Ss, off);
        Sr += __shfl_xor(Sr, off);
    }
    const float cs = 0.5f / Ss, cr = 0.5f / Sr;
    #pragma unroll
    for (int t = 0; t < 6; ++t)
        crow[lane + 64 * t] = __float2bfloat16(es[t] * cs + er[t] * cr);
}

// ---------------------------------------------------------------------------
// out = comb @ v : AO[b*LSEQ+i][h*64+d] bf16.  grid 384 x 256 (64 bh x 6 m)
__global__ __launch_bounds__(256) void gemm_out_kernel(
    const __hip_bfloat16* __restrict__ C,   // comb [64][384][384]
    const __hip_bfloat16* __restrict__ VT,  // [64][64][384]
    __hip_bfloat16* __restrict__ AO)
{
    const int bh = blockIdx.x / 6;
    const int bm = blockIdx.x % 6;
    const int wv = threadIdx.x >> 6;
    const int lane = threadIdx.x & 63;
    const int lr = lane & 15, quad = lane >> 4;
    const int m0 = bm * 64 + (wv & 1) * 32;
    const int n0 = (wv >> 1) * 32;
    const __hip_bfloat16* cb = C + (size_t)bh * LL2;
    const __hip_bfloat16* vb = VT + (size_t)bh * DKH * LSEQ;
    f32x4 acc[2][2];
    #pragma unroll
    for (int i = 0; i < 2; ++i)
        #pragma unroll
        for (int j = 0; j < 2; ++j) acc[i][j] = (f32x4){0.f, 0.f, 0.f, 0.f};
    #pragma unroll 4
    for (int k0 = 0; k0 < LSEQ; k0 += 32) {
        const int ka = k0 + quad * 8;
        bf16x8 a0 = load_frag(cb + (size_t)(m0 + lr) * LSEQ + ka);
        bf16x8 a1 = load_frag(cb + (size_t)(m0 + 16 + lr) * LSEQ + ka);
        bf16x8 b0 = load_frag(vb + (size_t)(n0 + lr) * LSEQ + ka);
        bf16x8 b1 = load_frag(vb + (size_t)(n0 + 16 + lr) * LSEQ + ka);
        acc[0][0] = mfma16(a0, b0, acc[0][0]);
        acc[0][1] = mfma16(a0, b1, acc[0][1]);
        acc[1][0] = mfma16(a1, b0, acc[1][0]);
        acc[1][1] = mfma16(a1, b1, acc[1][1]);
    }
    const int bb = bh >> 3, hh = bh & 7;
    #pragma unroll
    for (int mi = 0; mi < 2; ++mi)
        #pragma unroll
        for (int ni = 0; ni < 2; ++ni)
            #pragma unroll
            for (int r = 0; r < 4; ++r) {
                const int m = m0 + mi * 16 + quad * 4 + r;
                const int n = n0 + ni * 16 + lr;
                AO[(size_t)(bb * LSEQ + m) * HID + hh * DKH + n] =
                    __float2bfloat16(acc[mi][ni][r]);
            }
}

// ---------------------------------------------------------------------------
// LayerNorm. flags: 1=add proj, 2=zero masked rows, 4=write bf16. grid 3072 x 256
__global__ __launch_bounds__(256) void ln_kernel(
    const float* __restrict__ resid, const float* __restrict__ proj,
    const float* __restrict__ g, const float* __restrict__ beta,
    float* __restrict__ outf, __hip_bfloat16* __restrict__ outb,
    const unsigned char* __restrict__ mask, int flags)
{
    const int row = blockIdx.x, tid = threadIdx.x;
    const size_t base = (size_t)row * HID;
    float x0 = resid[base + tid], x1 = resid[base + tid + 256];
    if (flags & 1) { x0 += proj[base + tid]; x1 += proj[base + tid + 256]; }
    float s = x0 + x1, s2 = x0 * x0 + x1 * x1;
    #pragma unroll
    for (int off = 32; off > 0; off >>= 1) {
        s += __shfl_xor(s, off);
        s2 += __shfl_xor(s2, off);
    }
    __shared__ float rs[4], rs2[4];
    if ((tid & 63) == 0) { rs[tid >> 6] = s; rs2[tid >> 6] = s2; }
    __syncthreads();
    s = rs[0] + rs[1] + rs[2] + rs[3];
    s2 = rs2[0] + rs2[1] + rs2[2] + rs2[3];
    const float mu = s * (1.f / HID);
    const float var = s2 * (1.f / HID) - mu * mu;
    const float rstd = rsqrtf(var + 1e-5f);
    float y0 = (x0 - mu) * rstd * g[tid] + beta[tid];
    float y1 = (x1 - mu) * rstd * g[tid + 256] + beta[tid + 256];
    if ((flags & 2) && !mask[row]) { y0 = 0.f; y1 = 0.f; }
    outf[base + tid] = y0;
    outf[base + tid + 256] = y1;
    if (flags & 4) {
        outb[base + tid] = __float2bfloat16(y0);
        outb[base + tid + 256] = __float2bfloat16(y1);
    }
}

// ---------------------------------------------------------------------------
// final reduce over sequence: out[b][c] = sum_l hfin[b][l][c] (fp32 out). grid 8 x 512
__global__ __launch_bounds__(512) void reduce_kernel(
    const float* __restrict__ hf, float* __restrict__ out)
{
    const int b = blockIdx.x, c = threadIdx.x;
    float s = 0.f;
    for (int i = 0; i < LSEQ; ++i)
        s += hf[((size_t)(b * LSEQ + i)) * HID + c];
    out[b * HID + c] = s;
}

// ---------------------------------------------------------------------------
extern "C" void kernel_launch(void* const* d_in, const int* in_sizes, int n_in,
                              void* d_out, int out_size, void* d_ws, size_t ws_size,
                              hipStream_t stream)
{
    const float* x   = (const float*)d_in[0];
    const unsigned char* mraw = (const unsigned char*)d_in[1];
    const float* refCov = (const float*)d_in[2];
    const float* Wq = (const float*)d_in[3];
    const float* bq = (const float*)d_in[4];
    const float* Wk = (const float*)d_in[5];
    const float* bk = (const float*)d_in[6];
    const float* Wv = (const float*)d_in[7];
    const float* bv = (const float*)d_in[8];
    const float* Wo = (const float*)d_in[9];
    const float* bo = (const float*)d_in[10];
    const float* Wr1 = (const float*)d_in[11];
    const float* br1 = (const float*)d_in[12];
    const float* Wr2 = (const float*)d_in[13];
    const float* br2 = (const float*)d_in[14];
    const float* ln_g = (const float*)d_in[15];
    const float* ln_b = (const float*)d_in[16];
    const float* fn_g = (const float*)d_in[17];
    const float* fn_b = (const float*)d_in[18];
    float* outp = (float*)d_out;

    char* ws = (char*)d_ws;
    size_t off = 0;
    auto alloc = [&](size_t bytes) -> char* {
        char* p = ws + off;
        off += (bytes + 255) & ~(size_t)255;
        return p;
    };
    __hip_bfloat16* refL = (__hip_bfloat16*)alloc((size_t)NLAY * BH * LL2 * 2);
    float*          h    = (float*)alloc((size_t)BL * HID * 4);
    __hip_bfloat16* hb   = (__hip_bfloat16*)alloc((size_t)BL * HID * 2);
    __hip_bfloat16* q    = (__hip_bfloat16*)alloc((size_t)BH * LSEQ * DKH * 2);
    __hip_bfloat16* kk   = (__hip_bfloat16*)alloc((size_t)BH * LSEQ * DKH * 2);
    __hip_bfloat16* vT   = (__hip_bfloat16*)alloc((size_t)BH * DKH * LSEQ * 2);
    float*          S    = (float*)alloc((size_t)BH * LL2 * 4);
    __hip_bfloat16* comb = (__hip_bfloat16*)alloc((size_t)BH * LL2 * 2);
    __hip_bfloat16* AO   = (__hip_bfloat16*)alloc((size_t)BL * HID * 2);
    float*          proj = (float*)alloc((size_t)BL * HID * 4);
    unsigned short* WT   = (unsigned short*)alloc((size_t)16 * HID * HID * 2);
    unsigned char*  msk  = (unsigned char*)alloc(BL);
    float*          hfin = S;   // S is dead by the final LN; alias it

    mask_norm_kernel<<<1, 1024, 0, stream>>>(mraw, msk);
    wconv_kernel<<<4096, 256, 0, stream>>>(Wq, Wk, Wv, Wo, WT);
    pack_kernel<<<6144, 256, 0, stream>>>(x, msk, h, hb);
    refmlp_kernel<<<4608, 256, 0, stream>>>(refCov, Wr1, br1, Wr2, br2, refL);

    for (int l = 0; l < NLAY; ++l) {
        const __hip_bfloat16* WTq = (const __hip_bfloat16*)(WT + (size_t)(0 * 4 + l) * HID * HID);
        const __hip_bfloat16* WTk = (const __hip_bfloat16*)(WT + (size_t)(1 * 4 + l) * HID * HID);
        const __hip_bfloat16* WTv = (const __hip_bfloat16*)(WT + (size_t)(2 * 4 + l) * HID * HID);
        const __hip_bfloat16* WTo = (const __hip_bfloat16*)(WT + (size_t)(3 * 4 + l) * HID * HID);
        gemm_proj_kernel<<<384, 256, 0, stream>>>(hb, WTq, bq + l * HID, q,  nullptr, 0, 0.125f);
        gemm_proj_kernel<<<384, 256, 0, stream>>>(hb, WTk, bk + l * HID, kk, nullptr, 1, 1.0f);
        gemm_proj_kernel<<<384, 256, 0, stream>>>(hb, WTv, bv + l * HID, vT, nullptr, 2, 1.0f);
        gemm_scores_kernel<<<2304, 256, 0, stream>>>(q, kk, S);
        softmax_comb_kernel<<<6144, 256, 0, stream>>>(S, refL + (size_t)l * BH * LL2, msk, comb);
        gemm_out_kernel<<<384, 256, 0, stream>>>(comb, vT, AO);
        gemm_proj_kernel<<<384, 256, 0, stream>>>(AO, WTo, bo + l * HID, nullptr, proj, 3, 1.0f);
        ln_kernel<<<3072, 256, 0, stream>>>(h, proj, ln_g + l * HID, ln_b + l * HID,
                                            h, hb, nullptr, 1 | 4);
    }
    ln_kernel<<<3072, 256, 0, stream>>>(h, nullptr, fn_g, fn_b, hfin, nullptr, msk, 2);
    reduce_kernel<<<8, 512, 0, stream>>>(hfin, outp);
}

// Round 7
// 907.094 us; speedup vs baseline: 1.3434x; 1.1585x over previous
//
#include <hip/hip_runtime.h>
#include <hip/hip_bf16.h>
#include <cstdint>

constexpr int LSEQ  = 384;
constexpr int BATCH = 8;
constexpr int HID   = 512;
constexpr int NHEAD = 8;
constexpr int DKH   = 64;
constexpr int NLAY  = 4;
constexpr int BL    = BATCH * LSEQ;      // 3072 rows
constexpr int LL2   = LSEQ * LSEQ;       // 147456 pairs per batch
constexpr int BH    = BATCH * NHEAD;     // 64

typedef __bf16 bf16x8 __attribute__((ext_vector_type(8)));
typedef float  f32x4  __attribute__((ext_vector_type(4)));
typedef unsigned short ushort_t;

__device__ inline bf16x8 load_frag(const void* p) {
    uint4 u = *reinterpret_cast<const uint4*>(p);
    return __builtin_bit_cast(bf16x8, u);
}
__device__ inline bf16x8 zero_frag() {
    uint4 u = {0u, 0u, 0u, 0u};
    return __builtin_bit_cast(bf16x8, u);
}
__device__ inline f32x4 mfma16(bf16x8 a, bf16x8 b, f32x4 c) {
    return __builtin_amdgcn_mfma_f32_16x16x32_bf16(a, b, c, 0, 0, 0);
}
__device__ inline float b2f(__hip_bfloat16 v) { return __bfloat162float(v); }
__device__ inline ushort_t bfbits(float f) {
    __hip_bfloat16 b = __float2bfloat16(f);
    return *(ushort_t*)&b;
}

// ---------------------------------------------------------------------------
// Normalize mask storage (u8 / i32 / i64 / bf16 / f32 bools) -> uchar[3072].
__global__ __launch_bounds__(1024) void mask_norm_kernel(
    const unsigned char* __restrict__ raw, unsigned char* __restrict__ m)
{
    __shared__ int fl;
    const int tid = threadIdx.x;
    if (tid == 0) fl = 0;
    __syncthreads();
    int f = 0;
    for (int i = tid; i < BL; i += 1024) {
        const unsigned char v = raw[i];
        if (v > 1) f |= 1;
        if (v && (i & 3)) f |= 2;
        if (v && ((i & 7) == 4)) f |= 4;
        if (v && ((i & 3) <= 1)) f |= 8;
    }
    if (f) atomicOr(&fl, f);
    __syncthreads();
    const int ff = fl;
    int stride, off;
    if (ff & 1) { if (ff & 8) { stride = 2; off = 0; } else { stride = 4; off = 2; } }
    else if (ff & 2) { stride = 1; off = 0; }
    else if (ff & 4) { stride = 4; off = 0; }
    else             { stride = 8; off = 0; }
    for (int i = tid; i < BL; i += 1024)
        m[i] = raw[(size_t)i * stride + off] ? 1 : 0;
}

// ---------------------------------------------------------------------------
// Weight convert+transpose: fp32 -> bf16, MFMA B-layout.
// QKV -> WTqkv[l][n'=1536][k=512] (n'<512:Q, <1024:K, else V); Wo -> WTo[l][512][512]
__global__ __launch_bounds__(256) void wconv_kernel(
    const float* __restrict__ Wq, const float* __restrict__ Wk,
    const float* __restrict__ Wv, const float* __restrict__ Wo,
    ushort_t* __restrict__ WTqkv, ushort_t* __restrict__ WTo)
{
    __shared__ float tile[32][33];
    const int t = blockIdx.x;
    const int ml = t >> 8;            // mat*4 + layer
    const int rest = t & 255;
    const int mi = ml >> 2, l = ml & 3;
    const int tk = (rest & 15) * 32;
    const int tn = (rest >> 4) * 32;
    const float* W = (mi == 0) ? Wq : (mi == 1) ? Wk : (mi == 2) ? Wv : Wo;
    const float* src = W + (size_t)l * HID * HID;
    const int c = threadIdx.x & 31, r = threadIdx.x >> 5;
    for (int rr = r; rr < 32; rr += 8)
        tile[rr][c] = src[(size_t)(tk + rr) * HID + tn + c];
    __syncthreads();
    ushort_t* dst = (mi < 3)
        ? WTqkv + ((size_t)l * 1536 + mi * 512) * HID
        : WTo   + (size_t)l * HID * HID;
    for (int rr = r; rr < 32; rr += 8)
        dst[(size_t)(tn + rr) * HID + tk + c] = bfbits(tile[c][rr]);
}

// ---------------------------------------------------------------------------
// refCov-MLP weights -> bf16 MFMA B-layout in global.
// W1T[l][n=32][k=64] (k>=53 zero), W2T[l][n=16][k=32] (n>=8 zero). grid 40x256.
__global__ __launch_bounds__(256) void refw_kernel(
    const float* __restrict__ Wr1, const float* __restrict__ Wr2,
    ushort_t* __restrict__ W1T, ushort_t* __restrict__ W2T)
{
    const int tid = blockIdx.x * 256 + threadIdx.x;
    if (tid < 4 * 32 * 64) {
        const int l = tid >> 11, rem = tid & 2047;
        const int n = rem >> 6, k = rem & 63;
        W1T[tid] = (k < 53) ? bfbits(Wr1[(l * 53 + k) * 32 + n]) : (ushort_t)0;
    } else if (tid < 4 * 32 * 64 + 4 * 16 * 32) {
        const int t2 = tid - 8192;
        const int l = t2 >> 9, rem = t2 & 511;
        const int n = rem >> 5, k = rem & 31;
        W2T[t2] = (n < 8) ? bfbits(Wr2[(l * 32 + k) * 8 + n]) : (ushort_t)0;
    }
}

// ---------------------------------------------------------------------------
// pack: h = x * mask (fp32 + bf16 copies). grid 6144 x 256
__global__ __launch_bounds__(256) void pack_kernel(
    const float* __restrict__ x, const unsigned char* __restrict__ mask,
    float* __restrict__ h, __hip_bfloat16* __restrict__ hb)
{
    const int idx = blockIdx.x * 256 + threadIdx.x;
    const int row = idx >> 9;
    const float v = mask[row] ? x[idx] : 0.f;
    h[idx] = v;
    hb[idx] = __float2bfloat16(v);
}

// ---------------------------------------------------------------------------
// refCov MLP v3: 256 pairs/block, A-frags register-resident, weights from
// global bf16, C1 overlays Atile, barrier-free layer loop. grid 4608 x 256.
__global__ __launch_bounds__(256) void refmlp_kernel(
    const float* __restrict__ refCov,
    const ushort_t* __restrict__ W1T, const float* __restrict__ br1,
    const ushort_t* __restrict__ W2T, const float* __restrict__ br2,
    __hip_bfloat16* __restrict__ refL)
{
    __shared__ ushort_t smem[256 * 56];   // 28672 B: Atile, later C1 overlay

    const int tid = threadIdx.x;
    const int w = tid >> 6, lane = tid & 63;
    const int lr = lane & 15, quad = lane >> 4;
    const size_t p0 = (size_t)blockIdx.x * 256;
    const int b = (int)(p0 / LL2);
    const int rem0 = (int)(p0 - (size_t)b * LL2);

    // ---- stage refCov block -> Atile[256][56] bf16 via float4 ----
    const float4* src4 = reinterpret_cast<const float4*>(refCov + p0 * 53);
    for (int f = tid; f < 3392; f += 256) {
        float4 v = src4[f];
        const int e = f * 4;
        #pragma unroll
        for (int k = 0; k < 4; ++k) {
            const int g = e + k;
            const int row = g / 53;
            const int col = g - row * 53;
            smem[row * 56 + col] = bfbits(((const float*)&v)[k]);
        }
    }
    smem[tid * 56 + 53] = 0;
    smem[tid * 56 + 54] = 0;
    smem[tid * 56 + 55] = 0;
    __syncthreads();

    // ---- A-fragments -> registers (held across all 4 layers) ----
    bf16x8 afr[4][2];
    #pragma unroll
    for (int mi = 0; mi < 4; ++mi) {
        const ushort_t* rp = smem + (w * 64 + mi * 16 + lr) * 56;
        afr[mi][0] = load_frag(rp + quad * 8);
        afr[mi][1] = (quad < 3) ? load_frag(rp + 32 + quad * 8) : zero_frag();
    }
    __syncthreads();   // all waves done with Atile; C1 overlay now safe

    ushort_t* C1w = smem + w * 2560;   // per-wave [64][40] bf16

    #pragma unroll
    for (int l = 0; l < NLAY; ++l) {
        const float bias0 = br1[l * 32 + lr];
        const float bias1 = br1[l * 32 + 16 + lr];
        const float bias2 = br2[l * 8 + (lr & 7)];
        bf16x8 w1f[2][2];
        #pragma unroll
        for (int ni = 0; ni < 2; ++ni)
            #pragma unroll
            for (int ks = 0; ks < 2; ++ks)
                w1f[ni][ks] = load_frag(W1T + ((l * 32 + ni * 16 + lr) * 64) + ks * 32 + quad * 8);
        bf16x8 w2f = load_frag(W2T + (l * 16 + lr) * 32 + quad * 8);

        // layer 1: 64x64(K) @ W1 -> 64x32
        f32x4 acc[4][2];
        #pragma unroll
        for (int mi = 0; mi < 4; ++mi) {
            acc[mi][0] = (f32x4){bias0, bias0, bias0, bias0};
            acc[mi][1] = (f32x4){bias1, bias1, bias1, bias1};
        }
        #pragma unroll
        for (int mi = 0; mi < 4; ++mi) {
            acc[mi][0] = mfma16(afr[mi][0], w1f[0][0], acc[mi][0]);
            acc[mi][0] = mfma16(afr[mi][1], w1f[0][1], acc[mi][0]);
            acc[mi][1] = mfma16(afr[mi][0], w1f[1][0], acc[mi][1]);
            acc[mi][1] = mfma16(afr[mi][1], w1f[1][1], acc[mi][1]);
        }
        // relu -> C1 (wave-local; DS in-order within wave, no barrier)
        #pragma unroll
        for (int mi = 0; mi < 4; ++mi)
            #pragma unroll
            for (int ni = 0; ni < 2; ++ni)
                #pragma unroll
                for (int r = 0; r < 4; ++r)
                    C1w[(mi * 16 + quad * 4 + r) * 40 + ni * 16 + lr] =
                        bfbits(fmaxf(acc[mi][ni][r], 0.f));

        // layer 2: 64x32 @ W2 -> 64x8, direct packed global store
        #pragma unroll
        for (int mi = 0; mi < 4; ++mi) {
            bf16x8 a2 = load_frag(C1w + (mi * 16 + lr) * 40 + quad * 8);
            f32x4 a = (f32x4){bias2, bias2, bias2, bias2};
            a = mfma16(a2, w2f, a);
            if (lr < 8) {
                uint2 pk;
                pk.x = (unsigned)bfbits(a[0]) | ((unsigned)bfbits(a[1]) << 16);
                pk.y = (unsigned)bfbits(a[2]) | ((unsigned)bfbits(a[3]) << 16);
                const size_t plane = ((size_t)(l * 8 + b) * 8 + lr) * LL2;
                *reinterpret_cast<uint2*>((ushort_t*)refL + plane + rem0 +
                                          w * 64 + mi * 16 + quad * 4) = pk;
            }
        }
    }
}

// ---------------------------------------------------------------------------
// Fused QKV GEMM: [3072,512] @ WTqkv^T[1536] -> q/k/vT. grid 1152 x 256.
__global__ __launch_bounds__(256) void gemm_qkv_kernel(
    const __hip_bfloat16* __restrict__ A,
    const __hip_bfloat16* __restrict__ BT,   // WTqkv + l*1536*512
    const float* __restrict__ bq, const float* __restrict__ bk,
    const float* __restrict__ bv,
    __hip_bfloat16* __restrict__ q, __hip_bfloat16* __restrict__ kk,
    __hip_bfloat16* __restrict__ vT)
{
    const int bm = blockIdx.x % (BL / 64);
    const int bn = blockIdx.x / (BL / 64);     // 0..23
    const int wv = threadIdx.x >> 6;
    const int lane = threadIdx.x & 63;
    const int lr = lane & 15, quad = lane >> 4;
    const int m0 = bm * 64 + (wv & 1) * 32;
    const int n0g = bn * 64 + (wv >> 1) * 32;  // global n' in [0,1536)
    f32x4 acc[2][2];
    #pragma unroll
    for (int i = 0; i < 2; ++i)
        #pragma unroll
        for (int j = 0; j < 2; ++j) acc[i][j] = (f32x4){0.f, 0.f, 0.f, 0.f};
    const __hip_bfloat16* a0p = A + (size_t)(m0 + lr) * HID;
    const __hip_bfloat16* a1p = A + (size_t)(m0 + 16 + lr) * HID;
    const __hip_bfloat16* b0p = BT + (size_t)(n0g + lr) * HID;
    const __hip_bfloat16* b1p = BT + (size_t)(n0g + 16 + lr) * HID;
    #pragma unroll 4
    for (int k0 = 0; k0 < HID; k0 += 32) {
        const int ka = k0 + quad * 8;
        bf16x8 a0 = load_frag(a0p + ka);
        bf16x8 a1 = load_frag(a1p + ka);
        bf16x8 b0 = load_frag(b0p + ka);
        bf16x8 b1 = load_frag(b1p + ka);
        acc[0][0] = mfma16(a0, b0, acc[0][0]);
        acc[0][1] = mfma16(a0, b1, acc[0][1]);
        acc[1][0] = mfma16(a1, b0, acc[1][0]);
        acc[1][1] = mfma16(a1, b1, acc[1][1]);
    }
    const int mat = n0g >> 9;                     // block stays in one mat
    const float* bias = (mat == 0) ? bq : (mat == 1) ? bk : bv;
    const float scale = (mat == 0) ? 0.125f : 1.0f;
    __hip_bfloat16* outp = (mat == 0) ? q : (mat == 1) ? kk : vT;
    #pragma unroll
    for (int mi = 0; mi < 2; ++mi)
        #pragma unroll
        for (int ni = 0; ni < 2; ++ni)
            #pragma unroll
            for (int r = 0; r < 4; ++r) {
                const int m = m0 + mi * 16 + quad * 4 + r;
                const int ng = n0g + ni * 16 + lr;
                const int n = ng & 511;
                float v = (acc[mi][ni][r] + bias[n]) * scale;
                const int bb = m / LSEQ, ii = m % LSEQ;
                const int hh = n >> 6, d = n & 63;
                if (mat == 2)
                    outp[((size_t)(bb * NHEAD + hh) * DKH + d) * LSEQ + ii] = __float2bfloat16(v);
                else
                    outp[((size_t)(bb * NHEAD + hh) * LSEQ + ii) * DKH + d] = __float2bfloat16(v);
            }
}

// ---------------------------------------------------------------------------
// O-projection: proj[3072,512] = AO @ WTo^T + bo (fp32 out). grid 384 x 256.
__global__ __launch_bounds__(256) void gemm_oproj_kernel(
    const __hip_bfloat16* __restrict__ A,
    const __hip_bfloat16* __restrict__ BT,
    const float* __restrict__ bias,
    float* __restrict__ outf)
{
    const int bm = blockIdx.x % (BL / 64);
    const int bn = blockIdx.x / (BL / 64);
    const int wv = threadIdx.x >> 6;
    const int lane = threadIdx.x & 63;
    const int lr = lane & 15, quad = lane >> 4;
    const int m0 = bm * 64 + (wv & 1) * 32;
    const int n0 = bn * 64 + (wv >> 1) * 32;
    f32x4 acc[2][2];
    #pragma unroll
    for (int i = 0; i < 2; ++i)
        #pragma unroll
        for (int j = 0; j < 2; ++j) acc[i][j] = (f32x4){0.f, 0.f, 0.f, 0.f};
    const __hip_bfloat16* a0p = A + (size_t)(m0 + lr) * HID;
    const __hip_bfloat16* a1p = A + (size_t)(m0 + 16 + lr) * HID;
    const __hip_bfloat16* b0p = BT + (size_t)(n0 + lr) * HID;
    const __hip_bfloat16* b1p = BT + (size_t)(n0 + 16 + lr) * HID;
    #pragma unroll 4
    for (int k0 = 0; k0 < HID; k0 += 32) {
        const int ka = k0 + quad * 8;
        bf16x8 a0 = load_frag(a0p + ka);
        bf16x8 a1 = load_frag(a1p + ka);
        bf16x8 b0 = load_frag(b0p + ka);
        bf16x8 b1 = load_frag(b1p + ka);
        acc[0][0] = mfma16(a0, b0, acc[0][0]);
        acc[0][1] = mfma16(a0, b1, acc[0][1]);
        acc[1][0] = mfma16(a1, b0, acc[1][0]);
        acc[1][1] = mfma16(a1, b1, acc[1][1]);
    }
    #pragma unroll
    for (int mi = 0; mi < 2; ++mi)
        #pragma unroll
        for (int ni = 0; ni < 2; ++ni)
            #pragma unroll
            for (int r = 0; r < 4; ++r) {
                const int m = m0 + mi * 16 + quad * 4 + r;
                const int n = n0 + ni * 16 + lr;
                outf[(size_t)m * HID + n] = acc[mi][ni][r] + bias[n];
            }
}

// ---------------------------------------------------------------------------
// scores: S[bh][i][j] = sum_d q[bh][i][d]*k[bh][j][d]  (q pre-scaled)
__global__ __launch_bounds__(256) void gemm_scores_kernel(
    const __hip_bfloat16* __restrict__ Q,
    const __hip_bfloat16* __restrict__ Km,
    float* __restrict__ S)
{
    const int bh = blockIdx.x / 36;
    const int t = blockIdx.x % 36;
    const int bm = t % 6, bn = t / 6;
    const int wv = threadIdx.x >> 6;
    const int lane = threadIdx.x & 63;
    const int lr = lane & 15, quad = lane >> 4;
    const int m0 = bm * 64 + (wv & 1) * 32;
    const int n0 = bn * 64 + (wv >> 1) * 32;
    const __hip_bfloat16* qb = Q + (size_t)bh * LSEQ * DKH;
    const __hip_bfloat16* kb = Km + (size_t)bh * LSEQ * DKH;
    f32x4 acc[2][2];
    #pragma unroll
    for (int i = 0; i < 2; ++i)
        #pragma unroll
        for (int j = 0; j < 2; ++j) acc[i][j] = (f32x4){0.f, 0.f, 0.f, 0.f};
    #pragma unroll
    for (int k0 = 0; k0 < DKH; k0 += 32) {
        const int ka = k0 + quad * 8;
        bf16x8 a0 = load_frag(qb + (size_t)(m0 + lr) * DKH + ka);
        bf16x8 a1 = load_frag(qb + (size_t)(m0 + 16 + lr) * DKH + ka);
        bf16x8 b0 = load_frag(kb + (size_t)(n0 + lr) * DKH + ka);
        bf16x8 b1 = load_frag(kb + (size_t)(n0 + 16 + lr) * DKH + ka);
        acc[0][0] = mfma16(a0, b0, acc[0][0]);
        acc[0][1] = mfma16(a0, b1, acc[0][1]);
        acc[1][0] = mfma16(a1, b0, acc[1][0]);
        acc[1][1] = mfma16(a1, b1, acc[1][1]);
    }
    float* srow = S + (size_t)bh * LL2;
    #pragma unroll
    for (int mi = 0; mi < 2; ++mi)
        #pragma unroll
        for (int ni = 0; ni < 2; ++ni)
            #pragma unroll
            for (int r = 0; r < 4; ++r) {
                const int m = m0 + mi * 16 + quad * 4 + r;
                const int n = n0 + ni * 16 + lr;
                srow[(size_t)m * LSEQ + n] = acc[mi][ni][r];
            }
}

// ---------------------------------------------------------------------------
// softmax+combine: comb = 0.5*(softmax(S_masked) + softmax(ref_masked)), bf16
__global__ __launch_bounds__(256) void softmax_comb_kernel(
    const float* __restrict__ S, const __hip_bfloat16* __restrict__ refl,
    const unsigned char* __restrict__ mask, __hip_bfloat16* __restrict__ comb)
{
    const int wv = threadIdx.x >> 6, lane = threadIdx.x & 63;
    const int row = blockIdx.x * 4 + wv;      // bh*LSEQ + i
    const int bh = row / LSEQ, i = row % LSEQ;
    const int b = bh >> 3;
    const size_t roff = (size_t)row * LSEQ;
    __hip_bfloat16* crow = comb + roff;
    if (!mask[b * LSEQ + i]) {
        const __hip_bfloat16 z = __float2bfloat16(0.f);
        #pragma unroll
        for (int t = 0; t < 6; ++t) crow[lane + 64 * t] = z;
        return;
    }
    const float* srow = S + roff;
    const __hip_bfloat16* rrow = refl + roff;
    float sv[6], rv[6];
    #pragma unroll
    for (int t = 0; t < 6; ++t) {
        const int j = lane + 64 * t;
        const bool vm = mask[b * LSEQ + j] != 0;
        sv[t] = vm ? srow[j] : -1e30f;
        rv[t] = vm ? b2f(rrow[j]) : -1e30f;
    }
    float ms = -1e30f, mr = -1e30f;
    #pragma unroll
    for (int t = 0; t < 6; ++t) { ms = fmaxf(ms, sv[t]); mr = fmaxf(mr, rv[t]); }
    #pragma unroll
    for (int off = 32; off > 0; off >>= 1) {
        ms = fmaxf(ms, __shfl_xor(ms, off));
        mr = fmaxf(mr, __shfl_xor(mr, off));
    }
    float es[6], er[6], Ss = 0.f, Sr = 0.f;
    #pragma unroll
    for (int t = 0; t < 6; ++t) {
        es[t] = __expf(sv[t] - ms); Ss += es[t];
        er[t] = __expf(rv[t] - mr); Sr += er[t];
    }
    #pragma unroll
    for (int off = 32; off > 0; off >>= 1) {
        Ss += __shfl_xor(Ss, off);
        Sr += __shfl_xor(Sr, off);
    }
    const float cs = 0.5f / Ss, cr = 0.5f / Sr;
    #pragma unroll
    for (int t = 0; t < 6; ++t)
        crow[lane + 64 * t] = __float2bfloat16(es[t] * cs + er[t] * cr);
}

// ---------------------------------------------------------------------------
// out = comb @ v : AO[b*LSEQ+i][h*64+d] bf16.  grid 384 x 256 (64 bh x 6 m)
__global__ __launch_bounds__(256) void gemm_out_kernel(
    const __hip_bfloat16* __restrict__ C,   // comb [64][384][384]
    const __hip_bfloat16* __restrict__ VT,  // [64][64][384]
    __hip_bfloat16* __restrict__ AO)
{
    const int bh = blockIdx.x / 6;
    const int bm = blockIdx.x % 6;
    const int wv = threadIdx.x >> 6;
    const int lane = threadIdx.x & 63;
    const int lr = lane & 15, quad = lane >> 4;
    const int m0 = bm * 64 + (wv & 1) * 32;
    const int n0 = (wv >> 1) * 32;
    const __hip_bfloat16* cb = C + (size_t)bh * LL2;
    const __hip_bfloat16* vb = VT + (size_t)bh * DKH * LSEQ;
    f32x4 acc[2][2];
    #pragma unroll
    for (int i = 0; i < 2; ++i)
        #pragma unroll
        for (int j = 0; j < 2; ++j) acc[i][j] = (f32x4){0.f, 0.f, 0.f, 0.f};
    #pragma unroll 4
    for (int k0 = 0; k0 < LSEQ; k0 += 32) {
        const int ka = k0 + quad * 8;
        bf16x8 a0 = load_frag(cb + (size_t)(m0 + lr) * LSEQ + ka);
        bf16x8 a1 = load_frag(cb + (size_t)(m0 + 16 + lr) * LSEQ + ka);
        bf16x8 b0 = load_frag(vb + (size_t)(n0 + lr) * LSEQ + ka);
        bf16x8 b1 = load_frag(vb + (size_t)(n0 + 16 + lr) * LSEQ + ka);
        acc[0][0] = mfma16(a0, b0, acc[0][0]);
        acc[0][1] = mfma16(a0, b1, acc[0][1]);
        acc[1][0] = mfma16(a1, b0, acc[1][0]);
        acc[1][1] = mfma16(a1, b1, acc[1][1]);
    }
    const int bb = bh >> 3, hh = bh & 7;
    #pragma unroll
    for (int mi = 0; mi < 2; ++mi)
        #pragma unroll
        for (int ni = 0; ni < 2; ++ni)
            #pragma unroll
            for (int r = 0; r < 4; ++r) {
                const int m = m0 + mi * 16 + quad * 4 + r;
                const int n = n0 + ni * 16 + lr;
                AO[(size_t)(bb * LSEQ + m) * HID + hh * DKH + n] =
                    __float2bfloat16(acc[mi][ni][r]);
            }
}

// ---------------------------------------------------------------------------
// LayerNorm. flags: 1=add proj, 2=zero masked rows, 4=write bf16. grid 3072 x 256
__global__ __launch_bounds__(256) void ln_kernel(
    const float* __restrict__ resid, const float* __restrict__ proj,
    const float* __restrict__ g, const float* __restrict__ beta,
    float* __restrict__ outf, __hip_bfloat16* __restrict__ outb,
    const unsigned char* __restrict__ mask, int flags)
{
    const int row = blockIdx.x, tid = threadIdx.x;
    const size_t base = (size_t)row * HID;
    float x0 = resid[base + tid], x1 = resid[base + tid + 256];
    if (flags & 1) { x0 += proj[base + tid]; x1 += proj[base + tid + 256]; }
    float s = x0 + x1, s2 = x0 * x0 + x1 * x1;
    #pragma unroll
    for (int off = 32; off > 0; off >>= 1) {
        s += __shfl_xor(s, off);
        s2 += __shfl_xor(s2, off);
    }
    __shared__ float rs[4], rs2[4];
    if ((tid & 63) == 0) { rs[tid >> 6] = s; rs2[tid >> 6] = s2; }
    __syncthreads();
    s = rs[0] + rs[1] + rs[2] + rs[3];
    s2 = rs2[0] + rs2[1] + rs2[2] + rs2[3];
    const float mu = s * (1.f / HID);
    const float var = s2 * (1.f / HID) - mu * mu;
    const float rstd = rsqrtf(var + 1e-5f);
    float y0 = (x0 - mu) * rstd * g[tid] + beta[tid];
    float y1 = (x1 - mu) * rstd * g[tid + 256] + beta[tid + 256];
    if ((flags & 2) && !mask[row]) { y0 = 0.f; y1 = 0.f; }
    outf[base + tid] = y0;
    outf[base + tid + 256] = y1;
    if (flags & 4) {
        outb[base + tid] = __float2bfloat16(y0);
        outb[base + tid + 256] = __float2bfloat16(y1);
    }
}

// ---------------------------------------------------------------------------
// final reduce over sequence: out[b][c] = sum_l hfin[b][l][c] (fp32 out). grid 8 x 512
__global__ __launch_bounds__(512) void reduce_kernel(
    const float* __restrict__ hf, float* __restrict__ out)
{
    const int b = blockIdx.x, c = threadIdx.x;
    float s = 0.f;
    for (int i = 0; i < LSEQ; ++i)
        s += hf[((size_t)(b * LSEQ + i)) * HID + c];
    out[b * HID + c] = s;
}

// ---------------------------------------------------------------------------
extern "C" void kernel_launch(void* const* d_in, const int* in_sizes, int n_in,
                              void* d_out, int out_size, void* d_ws, size_t ws_size,
                              hipStream_t stream)
{
    const float* x   = (const float*)d_in[0];
    const unsigned char* mraw = (const unsigned char*)d_in[1];
    const float* refCov = (const float*)d_in[2];
    const float* Wq = (const float*)d_in[3];
    const float* bq = (const float*)d_in[4];
    const float* Wk = (const float*)d_in[5];
    const float* bk = (const float*)d_in[6];
    const float* Wv = (const float*)d_in[7];
    const float* bv = (const float*)d_in[8];
    const float* Wo = (const float*)d_in[9];
    const float* bo = (const float*)d_in[10];
    const float* Wr1 = (const float*)d_in[11];
    const float* br1 = (const float*)d_in[12];
    const float* Wr2 = (const float*)d_in[13];
    const float* br2 = (const float*)d_in[14];
    const float* ln_g = (const float*)d_in[15];
    const float* ln_b = (const float*)d_in[16];
    const float* fn_g = (const float*)d_in[17];
    const float* fn_b = (const float*)d_in[18];
    float* outp = (float*)d_out;

    char* ws = (char*)d_ws;
    size_t off = 0;
    auto alloc = [&](size_t bytes) -> char* {
        char* p = ws + off;
        off += (bytes + 255) & ~(size_t)255;
        return p;
    };
    __hip_bfloat16* refL  = (__hip_bfloat16*)alloc((size_t)NLAY * BH * LL2 * 2);
    float*          h     = (float*)alloc((size_t)BL * HID * 4);
    __hip_bfloat16* hb    = (__hip_bfloat16*)alloc((size_t)BL * HID * 2);
    __hip_bfloat16* q     = (__hip_bfloat16*)alloc((size_t)BH * LSEQ * DKH * 2);
    __hip_bfloat16* kk    = (__hip_bfloat16*)alloc((size_t)BH * LSEQ * DKH * 2);
    __hip_bfloat16* vT    = (__hip_bfloat16*)alloc((size_t)BH * DKH * LSEQ * 2);
    float*          S     = (float*)alloc((size_t)BH * LL2 * 4);
    __hip_bfloat16* comb  = (__hip_bfloat16*)alloc((size_t)BH * LL2 * 2);
    __hip_bfloat16* AO    = (__hip_bfloat16*)alloc((size_t)BL * HID * 2);
    float*          proj  = (float*)alloc((size_t)BL * HID * 4);
    ushort_t*       WTqkv = (ushort_t*)alloc((size_t)NLAY * 1536 * HID * 2);
    ushort_t*       WTo   = (ushort_t*)alloc((size_t)NLAY * HID * HID * 2);
    ushort_t*       W1T   = (ushort_t*)alloc((size_t)4 * 32 * 64 * 2);
    ushort_t*       W2T   = (ushort_t*)alloc((size_t)4 * 16 * 32 * 2);
    unsigned char*  msk   = (unsigned char*)alloc(BL);
    float*          hfin  = S;   // S dead by final LN; alias

    mask_norm_kernel<<<1, 1024, 0, stream>>>(mraw, msk);
    wconv_kernel<<<4096, 256, 0, stream>>>(Wq, Wk, Wv, Wo, WTqkv, WTo);
    refw_kernel<<<40, 256, 0, stream>>>(Wr1, Wr2, W1T, W2T);
    pack_kernel<<<6144, 256, 0, stream>>>(x, msk, h, hb);
    refmlp_kernel<<<4608, 256, 0, stream>>>(refCov, W1T, br1, W2T, br2, refL);

    for (int l = 0; l < NLAY; ++l) {
        const __hip_bfloat16* WTl = (const __hip_bfloat16*)(WTqkv + (size_t)l * 1536 * HID);
        const __hip_bfloat16* WTol = (const __hip_bfloat16*)(WTo + (size_t)l * HID * HID);
        gemm_qkv_kernel<<<1152, 256, 0, stream>>>(hb, WTl, bq + l * HID, bk + l * HID,
                                                  bv + l * HID, q, kk, vT);
        gemm_scores_kernel<<<2304, 256, 0, stream>>>(q, kk, S);
        softmax_comb_kernel<<<6144, 256, 0, stream>>>(S, refL + (size_t)l * BH * LL2, msk, comb);
        gemm_out_kernel<<<384, 256, 0, stream>>>(comb, vT, AO);
        gemm_oproj_kernel<<<384, 256, 0, stream>>>(AO, WTol, bo + l * HID, proj);
        ln_kernel<<<3072, 256, 0, stream>>>(h, proj, ln_g + l * HID, ln_b + l * HID,
                                            h, hb, nullptr, 1 | 4);
    }
    ln_kernel<<<3072, 256, 0, stream>>>(h, nullptr, fn_g, fn_b, hfin, nullptr, msk, 2);
    reduce_kernel<<<8, 512, 0, stream>>>(hfin, outp);
}